// Round 1
// baseline (1225.814 us; speedup 1.0000x reference)
//
#include <hip/hip_runtime.h>
#include <math.h>

typedef unsigned short ushort_t;
typedef short short8 __attribute__((ext_vector_type(8)));
typedef float f32x4 __attribute__((ext_vector_type(4)));

#define MFMA16(a,b,c) __builtin_amdgcn_mfma_f32_16x16x32_bf16(a,b,c,0,0,0)

__device__ __forceinline__ ushort_t f2bf(float f){
  unsigned u = __builtin_bit_cast(unsigned, f);
  u += 0x7fffu + ((u >> 16) & 1u);
  return (ushort_t)(u >> 16);
}

__device__ __forceinline__ void gld16(const void* g, void* l){
  __builtin_amdgcn_global_load_lds(
      (const __attribute__((address_space(1))) void*)g,
      (__attribute__((address_space(3))) void*)l, 16, 0, 0);
}

// ---------------- weight prep ----------------
__global__ void convw(const float* __restrict__ w, const float* __restrict__ lnw,
                      ushort_t* __restrict__ o, int total, int kmask){
  int i = blockIdx.x*256 + threadIdx.x;
  if (i < total){
    float v = w[i];
    if (lnw) v *= lnw[i & kmask];
    o[i] = f2bf(v);
  }
}

__global__ void transw(const float* __restrict__ w, ushort_t* __restrict__ o){
  int i = blockIdx.x*256 + threadIdx.x;  // o[n][k] = w[k][n], 512x512
  int n = i >> 9, k = i & 511;
  o[i] = f2bf(w[(k << 9) + n]);
}

__global__ __launch_bounds__(64)
void biasfold(const float* __restrict__ w, const float* __restrict__ lnb,
              const float* __restrict__ base, float* __restrict__ o, int K){
  int n = blockIdx.x, lane = threadIdx.x;
  float s = 0.f;
  for (int k = lane; k < K; k += 64) s += w[(size_t)n*K + k]*lnb[k];
  for (int m = 32; m; m >>= 1) s += __shfl_xor(s, m);
  if (lane == 0) o[n] = s + (base ? base[n] : 0.f);
}

// ---------------- per-row LN stats ----------------
__global__ __launch_bounds__(256)
void rowstats(const float* __restrict__ X, float* __restrict__ mu, float* __restrict__ rstd){
  int row = blockIdx.x*4 + (threadIdx.x >> 6);
  int lane = threadIdx.x & 63;
  const float4* p = (const float4*)(X + (size_t)row*512 + lane*8);
  float4 a = p[0], c = p[1];
  float s = a.x+a.y+a.z+a.w + c.x+c.y+c.z+c.w;
  float q = a.x*a.x+a.y*a.y+a.z*a.z+a.w*a.w + c.x*c.x+c.y*c.y+c.z*c.z+c.w*c.w;
  for (int m = 32; m; m >>= 1){ s += __shfl_xor(s, m); q += __shfl_xor(q, m); }
  if (lane == 0){
    float mn = s*(1.f/512.f);
    mu[row] = mn;
    rstd[row] = rsqrtf(q*(1.f/512.f) - mn*mn + 1e-5f);
  }
}

// ---------------- GEMM: C[M,N] = A[M,K] * Bt[N,K]^T ----------------
// AMODE 0: A is bf16 row-major (global_load_lds)
// AMODE 1: A is fp32 row-major, LN applied: (a-mu[row])*rstd[row], reg-staged
// EPI 0: bf16 out (+bias)     1: fp32 out
// EPI 2: fp32 out = acc+bias+resid   3: bf16 out = gelu(acc+bias)
// EPI 4: KV split: cols<512 -> bf16 K[M,512]; cols>=512 -> Vt[b,h,d,m] (out2)
template<int AMODE, int EPI>
__global__ __launch_bounds__(256)
void gemm_k(const void* __restrict__ Ap, const float* __restrict__ Amu,
            const float* __restrict__ Arstd, const ushort_t* __restrict__ Bt,
            int M, int N, int K,
            const float* __restrict__ bias, const float* __restrict__ resid,
            void* __restrict__ out, void* __restrict__ out2)
{
  __shared__ __align__(16) ushort_t As[128*64];
  __shared__ __align__(16) ushort_t Bs[128*64];
  const int tid = threadIdx.x;
  const int wave = tid >> 6, lane = tid & 63;
  const int tiles_n = N >> 7;
  const int tn = blockIdx.x % tiles_n, tm = blockIdx.x / tiles_n;
  const int wm = wave >> 1, wn = wave & 1;
  const int segr = lane >> 3;        // row within 8-row segment
  const int kcol = (lane & 7)*8;     // k element within row

  f32x4 acc[4][4] = {};

  for (int kt = 0; kt < K; kt += 64){
    // stage B (always bf16)
    for (int i = 0; i < 4; i++){
      int seg = wave*4 + i;
      int row = seg*8 + segr;
      gld16(Bt + (size_t)(tn*128 + row)*K + kt + kcol, (void*)(Bs + seg*512));
    }
    if constexpr (AMODE == 0){
      const ushort_t* Ab = (const ushort_t*)Ap;
      for (int i = 0; i < 4; i++){
        int seg = wave*4 + i;
        int row = seg*8 + segr;
        gld16(Ab + (size_t)(tm*128 + row)*K + kt + kcol, (void*)(As + seg*512));
      }
    } else {
      const float* Af = (const float*)Ap;
      for (int i = 0; i < 4; i++){
        int seg = wave*4 + i;
        int row = seg*8 + segr;
        int grow = tm*128 + row;
        const float* rp = Af + (size_t)grow*K + kt + kcol;
        float4 v0 = *(const float4*)rp;
        float4 v1 = *(const float4*)(rp + 4);
        float mu = Amu[grow], rs = Arstd[grow];
        short8 pk;
        pk[0]=(short)f2bf((v0.x-mu)*rs); pk[1]=(short)f2bf((v0.y-mu)*rs);
        pk[2]=(short)f2bf((v0.z-mu)*rs); pk[3]=(short)f2bf((v0.w-mu)*rs);
        pk[4]=(short)f2bf((v1.x-mu)*rs); pk[5]=(short)f2bf((v1.y-mu)*rs);
        pk[6]=(short)f2bf((v1.z-mu)*rs); pk[7]=(short)f2bf((v1.w-mu)*rs);
        *(short8*)&As[row*64 + kcol] = pk;
      }
    }
    __syncthreads();
    for (int kk = 0; kk < 2; kk++){
      int kc = kk*32 + (lane >> 4)*8;
      short8 af[4], bfr[4];
      for (int mi = 0; mi < 4; mi++)
        af[mi] = *(const short8*)&As[(wm*64 + mi*16 + (lane & 15))*64 + kc];
      for (int ni = 0; ni < 4; ni++)
        bfr[ni] = *(const short8*)&Bs[(wn*64 + ni*16 + (lane & 15))*64 + kc];
      for (int mi = 0; mi < 4; mi++)
        for (int ni = 0; ni < 4; ni++)
          acc[mi][ni] = MFMA16(af[mi], bfr[ni], acc[mi][ni]);
    }
    __syncthreads();
  }

  // epilogue
  for (int ni = 0; ni < 4; ni++){
    int col = tn*128 + wn*64 + ni*16 + (lane & 15);
    float bv = bias ? bias[col] : 0.f;
    for (int mi = 0; mi < 4; mi++){
      f32x4 v = acc[mi][ni];
      int row0 = tm*128 + wm*64 + mi*16 + (lane >> 4)*4;
      if constexpr (EPI == 4){
        if (col < 512){
          for (int j = 0; j < 4; j++){
            size_t idx = (size_t)(row0 + j)*512 + col;
            ((ushort_t*)out)[idx] = f2bf(v[j] + bv);
          }
        } else {
          int hh = (col - 512) >> 6, dd = (col - 512) & 63;
          int bb = row0 >> 6, mm0 = row0 & 63;
          ushort_t pk[4];
          for (int j = 0; j < 4; j++) pk[j] = f2bf(v[j] + bv);
          // 4 consecutive m -> one 8B store
          *(uint2*)((ushort_t*)out2 + ((((size_t)bb*8 + hh)*64 + dd) << 6) + mm0) =
              *(const uint2*)pk;
        }
      } else {
        for (int j = 0; j < 4; j++){
          int row = row0 + j;
          size_t idx = (size_t)row*N + col;
          float x = v[j] + bv;
          if constexpr (EPI == 0) ((ushort_t*)out)[idx] = f2bf(x);
          else if constexpr (EPI == 1) ((float*)out)[idx] = x;
          else if constexpr (EPI == 2) ((float*)out)[idx] = x + resid[idx];
          else if constexpr (EPI == 3){
            float g = 0.5f*x*(1.f + erff(x*0.70710678118f));
            ((ushort_t*)out)[idx] = f2bf(g);
          }
        }
      }
    }
  }
}

// ---------------- batched QK^T:  S[b,n,h*64+m] = SCALE * sum_d Q K ----------------
__global__ __launch_bounds__(256)
void qk_kernel(const ushort_t* __restrict__ Q, const ushort_t* __restrict__ Kb,
               ushort_t* __restrict__ S)
{
  int b = blockIdx.x;
  int wave = threadIdx.x >> 6, lane = threadIdx.x & 63;
  for (int h = wave; h < 8; h += 4){
    f32x4 acc[2][4] = {};
    for (int kk = 0; kk < 2; kk++){
      int kd = kk*32 + (lane >> 4)*8;
      short8 a[2], bb[4];
      for (int mi = 0; mi < 2; mi++){
        int n = mi*16 + (lane & 15); if (n > 16) n = 16;
        a[mi] = *(const short8*)&Q[((size_t)b*17 + n)*512 + h*64 + kd];
      }
      for (int ni = 0; ni < 4; ni++){
        int m = ni*16 + (lane & 15);
        bb[ni] = *(const short8*)&Kb[((size_t)b*64 + m)*512 + h*64 + kd];
      }
      for (int mi = 0; mi < 2; mi++)
        for (int ni = 0; ni < 4; ni++)
          acc[mi][ni] = MFMA16(a[mi], bb[ni], acc[mi][ni]);
    }
    for (int mi = 0; mi < 2; mi++)
      for (int ni = 0; ni < 4; ni++)
        for (int j = 0; j < 4; j++){
          int rr = mi*16 + (lane >> 4)*4 + j;
          if (rr < 17)
            S[((size_t)b*17 + rr)*512 + h*64 + ni*16 + (lane & 15)] =
                f2bf(acc[mi][ni][j]*0.125f);
        }
  }
}

// ---------------- batched PV: X[b,n,h*64+d] = sum_m P V ----------------
__global__ __launch_bounds__(256)
void pv_kernel(const ushort_t* __restrict__ P, const ushort_t* __restrict__ Vt,
               ushort_t* __restrict__ X)
{
  int b = blockIdx.x;
  int wave = threadIdx.x >> 6, lane = threadIdx.x & 63;
  for (int h = wave; h < 8; h += 4){
    f32x4 acc[2][4] = {};
    for (int kk = 0; kk < 2; kk++){
      int km = kk*32 + (lane >> 4)*8;
      short8 a[2], bb[4];
      for (int mi = 0; mi < 2; mi++){
        int n = mi*16 + (lane & 15); if (n > 16) n = 16;
        a[mi] = *(const short8*)&P[((size_t)b*17 + n)*512 + h*64 + km];
      }
      for (int ni = 0; ni < 4; ni++){
        int d = ni*16 + (lane & 15);
        bb[ni] = *(const short8*)&Vt[(((size_t)b*8 + h)*64 + d)*64 + km];
      }
      for (int mi = 0; mi < 2; mi++)
        for (int ni = 0; ni < 4; ni++)
          acc[mi][ni] = MFMA16(a[mi], bb[ni], acc[mi][ni]);
    }
    for (int mi = 0; mi < 2; mi++)
      for (int ni = 0; ni < 4; ni++)
        for (int j = 0; j < 4; j++){
          int rr = mi*16 + (lane >> 4)*4 + j;
          if (rr < 17)
            X[((size_t)b*17 + rr)*512 + h*64 + ni*16 + (lane & 15)] =
                f2bf(acc[mi][ni][j]);
        }
  }
}

// ---------------- BatchNorm stats ----------------
__global__ __launch_bounds__(256)
void bn_stats(const float* __restrict__ preBN, float* __restrict__ sums){
  int t = threadIdx.x;
  size_t base = (size_t)blockIdx.x * 256 * 512;
  int c0 = t, c1 = t + 256;
  float s0=0, q0=0, s1=0, q1=0;
  for (int r = 0; r < 256; r++){
    float a = preBN[base + (size_t)r*512 + c0];
    float b = preBN[base + (size_t)r*512 + c1];
    s0 += a; q0 += a*a; s1 += b; q1 += b*b;
  }
  atomicAdd(&sums[c0], s0);       atomicAdd(&sums[512 + c0], q0);
  atomicAdd(&sums[c1], s1);       atomicAdd(&sums[512 + c1], q1);
}

__global__ void bn_finalize(const float* __restrict__ sums, const float* __restrict__ g,
                            const float* __restrict__ b, float* __restrict__ scale,
                            float* __restrict__ shift, float invN){
  int c = blockIdx.x*256 + threadIdx.x;
  if (c < 512){
    float mean = sums[c]*invN;
    float var  = sums[512 + c]*invN - mean*mean;
    float sc = g[c]*rsqrtf(var + 1e-5f);
    scale[c] = sc; shift[c] = b[c] - mean*sc;
  }
}

// ---------------- BN apply + adjacency mix + softmax ----------------
__constant__ unsigned ADJM[17] = {
  0x7u, 0xFu, 0x17u, 0x2Au, 0x54u, 0x8E8u, 0x1170u, 0x2A0u, 0x540u,
  0x280u, 0x500u, 0x3820u, 0x5840u, 0xA800u, 0x15000u, 0xA000u, 0x14000u };

__global__ __launch_bounds__(256)
void bn_adj_softmax(const float* __restrict__ preBN, const float* __restrict__ scale,
                    const float* __restrict__ shift, ushort_t* __restrict__ Asm)
{
  __shared__ float yt[17*512];
  int b = blockIdx.x, tid = threadIdx.x;
  const float* src = preBN + (size_t)b*17*512;
  for (int i = tid; i < 17*512; i += 256){
    int c = i & 511;
    yt[i] = src[i]*scale[c] + shift[c];
  }
  __syncthreads();
  int qw = tid >> 4, l16 = tid & 15;
  for (int g = qw; g < 136; g += 16){
    int n = g >> 3, h = g & 7;
    float z[4];
    unsigned msk = ADJM[n];
    for (int u = 0; u < 4; u++){
      int c = h*64 + l16 + u*16;
      float sv = 0.f;
      unsigned mm = msk;
      while (mm){ int j = __ffs(mm) - 1; mm &= mm - 1; sv += yt[j*512 + c]; }
      z[u] = sv;
    }
    float mx = fmaxf(fmaxf(z[0], z[1]), fmaxf(z[2], z[3]));
    for (int m = 8; m; m >>= 1) mx = fmaxf(mx, __shfl_xor(mx, m, 16));
    float e0 = expf(z[0]-mx), e1 = expf(z[1]-mx), e2 = expf(z[2]-mx), e3 = expf(z[3]-mx);
    float ss = e0 + e1 + e2 + e3;
    for (int m = 8; m; m >>= 1) ss += __shfl_xor(ss, m, 16);
    float inv = 1.f/ss;
    size_t ob = ((size_t)b*17 + n)*512 + h*64 + l16;
    Asm[ob]      = f2bf(e0*inv);
    Asm[ob + 16] = f2bf(e1*inv);
    Asm[ob + 32] = f2bf(e2*inv);
    Asm[ob + 48] = f2bf(e3*inv);
  }
}

// ---------------- host ----------------
extern "C" void kernel_launch(void* const* d_in, const int* in_sizes, int n_in,
                              void* d_out, int out_size, void* d_ws, size_t ws_size,
                              hipStream_t stream)
{
  const float* noise  = (const float*)d_in[0];
  const float* obj    = (const float*)d_in[1];
  const float* ln1w   = (const float*)d_in[2];
  const float* ln1b   = (const float*)d_in[3];
  const float* ln2w   = (const float*)d_in[4];
  const float* ln2b   = (const float*)d_in[5];
  const float* q_w    = (const float*)d_in[6];
  const float* kv_w   = (const float*)d_in[7];
  const float* Wm     = (const float*)d_in[8];
  const float* bn_g   = (const float*)d_in[9];
  const float* bn_b   = (const float*)d_in[10];
  const float* proj_w = (const float*)d_in[11];
  const float* proj_b = (const float*)d_in[12];
  const float* fc1_w  = (const float*)d_in[13];
  const float* fc1_b  = (const float*)d_in[14];
  const float* fc2_w  = (const float*)d_in[15];
  const float* fc2_b  = (const float*)d_in[16];

  const int B  = in_sizes[0] / (17*512);   // 2048
  const int M  = B*17;                     // 34816
  const int MO = B*64;                     // 131072

  char* ws = (char*)d_ws;
  size_t off = 0;
  auto alloc = [&](size_t bytes)->char*{
    char* p = ws + off; off += (bytes + 255) & ~(size_t)255; return p; };

  ushort_t* q_wb    = (ushort_t*)alloc((size_t)512*512*2);
  ushort_t* kv_wb   = (ushort_t*)alloc((size_t)1024*512*2);
  ushort_t* proj_wb = (ushort_t*)alloc((size_t)512*512*2);
  ushort_t* fc1_wb  = (ushort_t*)alloc((size_t)2048*512*2);
  ushort_t* fc2_wb  = (ushort_t*)alloc((size_t)512*2048*2);
  ushort_t* Wt_b    = (ushort_t*)alloc((size_t)512*512*2);
  float* qbias   = (float*)alloc(512*4);
  float* kvbias  = (float*)alloc(1024*4);
  float* fc1bias = (float*)alloc(2048*4);
  float* mu_n  = (float*)alloc((size_t)M*4);
  float* rs_n  = (float*)alloc((size_t)M*4);
  float* mu_o  = (float*)alloc((size_t)MO*4);
  float* rs_o  = (float*)alloc((size_t)MO*4);
  float* mu_x  = (float*)alloc((size_t)M*4);
  float* rs_x  = (float*)alloc((size_t)M*4);
  float* bnsum   = (float*)alloc(1024*4);
  float* bnscale = (float*)alloc(512*4);
  float* bnshift = (float*)alloc(512*4);
  ushort_t* Qb  = (ushort_t*)alloc((size_t)M*512*2);   // reused as A_sm
  ushort_t* Kb  = (ushort_t*)alloc((size_t)MO*512*2);  // (+Vtb) reused as h1
  ushort_t* Vtb = (ushort_t*)alloc((size_t)B*8*64*64*2);
  ushort_t* Sb  = (ushort_t*)alloc((size_t)M*512*2);   // reused as PVo
  float*  preBN = (float*)alloc((size_t)M*512*4);      // reused as xres
  ushort_t* h1  = Kb;
  ushort_t* Asm = Qb;
  ushort_t* PVo = Sb;
  float*  xres  = preBN;
  float*  outp  = (float*)d_out;

  // ---- prep ----
  hipMemsetAsync(bnsum, 0, 1024*4, stream);
  convw<<<dim3((512*512)/256), 256, 0, stream>>>(q_w,  ln1w, q_wb,  512*512, 511);
  convw<<<dim3((1024*512)/256),256, 0, stream>>>(kv_w, ln1w, kv_wb, 1024*512, 511);
  convw<<<dim3((512*512)/256), 256, 0, stream>>>(proj_w, nullptr, proj_wb, 512*512, 511);
  convw<<<dim3((2048*512)/256),256, 0, stream>>>(fc1_w, ln2w, fc1_wb, 2048*512, 511);
  convw<<<dim3((512*2048)/256),256, 0, stream>>>(fc2_w, nullptr, fc2_wb, 512*2048, 2047);
  transw<<<dim3((512*512)/256), 256, 0, stream>>>(Wm, Wt_b);
  biasfold<<<dim3(512),  64, 0, stream>>>(q_w,  ln1b, nullptr, qbias,  512);
  biasfold<<<dim3(1024), 64, 0, stream>>>(kv_w, ln1b, nullptr, kvbias, 512);
  biasfold<<<dim3(2048), 64, 0, stream>>>(fc1_w, ln2b, fc1_b, fc1bias, 512);
  rowstats<<<dim3(M/4),  256, 0, stream>>>(noise, mu_n, rs_n);
  rowstats<<<dim3(MO/4), 256, 0, stream>>>(obj,   mu_o, rs_o);

  // ---- attention branch ----
  gemm_k<1,0><<<dim3((M/128)*(512/128)), 256, 0, stream>>>(
      noise, mu_n, rs_n, q_wb, M, 512, 512, qbias, nullptr, Qb, nullptr);
  gemm_k<1,4><<<dim3((MO/128)*(1024/128)), 256, 0, stream>>>(
      obj, mu_o, rs_o, kv_wb, MO, 1024, 512, kvbias, nullptr, Kb, Vtb);
  qk_kernel<<<dim3(B), 256, 0, stream>>>(Qb, Kb, Sb);
  gemm_k<0,1><<<dim3((M/128)*(512/128)), 256, 0, stream>>>(
      Sb, nullptr, nullptr, Wt_b, M, 512, 512, nullptr, nullptr, preBN, nullptr);
  bn_stats<<<dim3(M/256), 256, 0, stream>>>(preBN, bnsum);
  bn_finalize<<<dim3(2), 256, 0, stream>>>(bnsum, bn_g, bn_b, bnscale, bnshift, 1.f/(float)M);
  bn_adj_softmax<<<dim3(B), 256, 0, stream>>>(preBN, bnscale, bnshift, Asm);
  pv_kernel<<<dim3(B), 256, 0, stream>>>(Asm, Vtb, PVo);
  gemm_k<0,2><<<dim3((M/128)*(512/128)), 256, 0, stream>>>(
      PVo, nullptr, nullptr, proj_wb, M, 512, 512, proj_b, noise, xres, nullptr);

  // ---- MLP branch ----
  rowstats<<<dim3(M/4), 256, 0, stream>>>(xres, mu_x, rs_x);
  gemm_k<1,3><<<dim3((M/128)*(2048/128)), 256, 0, stream>>>(
      xres, mu_x, rs_x, fc1_wb, M, 2048, 512, fc1bias, nullptr, h1, nullptr);
  gemm_k<0,2><<<dim3((M/128)*(512/128)), 256, 0, stream>>>(
      h1, nullptr, nullptr, fc2_wb, M, 512, 2048, fc2_b, xres, outp, nullptr);
}

// Round 2
// 1010.554 us; speedup vs baseline: 1.2130x; 1.2130x over previous
//
#include <hip/hip_runtime.h>
#include <math.h>

typedef unsigned short ushort_t;
typedef short short8 __attribute__((ext_vector_type(8)));
typedef float f32x4 __attribute__((ext_vector_type(4)));

#define MFMA16(a,b,c) __builtin_amdgcn_mfma_f32_16x16x32_bf16(a,b,c,0,0,0)

__device__ __forceinline__ ushort_t f2bf(float f){
  unsigned u = __builtin_bit_cast(unsigned, f);
  u += 0x7fffu + ((u >> 16) & 1u);
  return (ushort_t)(u >> 16);
}

__device__ __forceinline__ void gld16(const void* g, void* l){
  __builtin_amdgcn_global_load_lds(
      (const __attribute__((address_space(1))) void*)g,
      (__attribute__((address_space(3))) void*)l, 16, 0, 0);
}

// ---------------- weight prep ----------------
__global__ void convw(const float* __restrict__ w, const float* __restrict__ lnw,
                      ushort_t* __restrict__ o, int total, int kmask){
  int i = blockIdx.x*256 + threadIdx.x;
  if (i < total){
    float v = w[i];
    if (lnw) v *= lnw[i & kmask];
    o[i] = f2bf(v);
  }
}

__global__ void transw(const float* __restrict__ w, ushort_t* __restrict__ o){
  int i = blockIdx.x*256 + threadIdx.x;  // o[n][k] = w[k][n], 512x512
  int n = i >> 9, k = i & 511;
  o[i] = f2bf(w[(k << 9) + n]);
}

__global__ __launch_bounds__(64)
void biasfold(const float* __restrict__ w, const float* __restrict__ lnb,
              const float* __restrict__ base, float* __restrict__ o, int K){
  int n = blockIdx.x, lane = threadIdx.x;
  float s = 0.f;
  for (int k = lane; k < K; k += 64) s += w[(size_t)n*K + k]*lnb[k];
  for (int m = 32; m; m >>= 1) s += __shfl_xor(s, m);
  if (lane == 0) o[n] = s + (base ? base[n] : 0.f);
}

// ---------------- fused LN stats + normalize -> bf16 ----------------
__global__ __launch_bounds__(256)
void lnorm(const float* __restrict__ X, ushort_t* __restrict__ O){
  int row = blockIdx.x*4 + (threadIdx.x >> 6);
  int lane = threadIdx.x & 63;
  const float4* p = (const float4*)(X + (size_t)row*512 + lane*8);
  float4 a = p[0], c = p[1];
  float s = a.x+a.y+a.z+a.w + c.x+c.y+c.z+c.w;
  float q = a.x*a.x+a.y*a.y+a.z*a.z+a.w*a.w + c.x*c.x+c.y*c.y+c.z*c.z+c.w*c.w;
  for (int m = 32; m; m >>= 1){ s += __shfl_xor(s, m); q += __shfl_xor(q, m); }
  float mn = s*(1.f/512.f);
  float rs = rsqrtf(q*(1.f/512.f) - mn*mn + 1e-5f);
  short8 pk;
  pk[0]=(short)f2bf((a.x-mn)*rs); pk[1]=(short)f2bf((a.y-mn)*rs);
  pk[2]=(short)f2bf((a.z-mn)*rs); pk[3]=(short)f2bf((a.w-mn)*rs);
  pk[4]=(short)f2bf((c.x-mn)*rs); pk[5]=(short)f2bf((c.y-mn)*rs);
  pk[6]=(short)f2bf((c.z-mn)*rs); pk[7]=(short)f2bf((c.w-mn)*rs);
  *(short8*)(O + (size_t)row*512 + lane*8) = pk;
}

// ---------------- GEMM: C[M,N] = A[M,K] * Bt[N,K]^T (A,Bt bf16) ----------------
// LDS tiles XOR-swizzled: slot (row, u) holds global (row, u ^ ((row&7)<<3)).
// Staged via pre-swizzled global source addresses (gld16 dest stays linear).
// EPI 0: bf16 out (+bias)             1: fp32 out
// EPI 2: fp32 out = acc+bias+resid    3: bf16 out = gelu(acc+bias)
// EPI 4: KV split: cols<512 -> bf16 K[M,512]; cols>=512 -> Vt[b,h,d,m] (out2)
template<int EPI>
__global__ __launch_bounds__(256)
void gemm_k(const ushort_t* __restrict__ A, const ushort_t* __restrict__ Bt,
            int M, int N, int K,
            const float* __restrict__ bias, const float* __restrict__ resid,
            void* __restrict__ out, void* __restrict__ out2)
{
  __shared__ __align__(16) ushort_t As[128*64];
  __shared__ __align__(16) ushort_t Bs[128*64];
  const int tid = threadIdx.x;
  const int wave = tid >> 6, lane = tid & 63;
  const int tiles_n = N >> 7;
  const int tn = blockIdx.x % tiles_n, tm = blockIdx.x / tiles_n;
  const int wm = wave >> 1, wn = wave & 1;
  const int segr = lane >> 3;                    // row within 8-row segment
  const int ksw  = ((lane & 7) ^ segr) * 8;      // pre-swizzled k source col

  f32x4 acc[4][4] = {};

  for (int kt = 0; kt < K; kt += 64){
    for (int i = 0; i < 4; i++){
      int seg = wave*4 + i;
      int row = seg*8 + segr;
      gld16(Bt + (size_t)(tn*128 + row)*K + kt + ksw, (void*)(Bs + seg*512));
      gld16(A  + (size_t)(tm*128 + row)*K + kt + ksw, (void*)(As + seg*512));
    }
    __syncthreads();
    for (int kk = 0; kk < 2; kk++){
      int kc = kk*32 + (lane >> 4)*8;
      short8 af[4], bfr[4];
      for (int mi = 0; mi < 4; mi++){
        int r = wm*64 + mi*16 + (lane & 15);
        af[mi] = *(const short8*)&As[r*64 + (kc ^ ((r & 7) << 3))];
      }
      for (int ni = 0; ni < 4; ni++){
        int r = wn*64 + ni*16 + (lane & 15);
        bfr[ni] = *(const short8*)&Bs[r*64 + (kc ^ ((r & 7) << 3))];
      }
      for (int mi = 0; mi < 4; mi++)
        for (int ni = 0; ni < 4; ni++)
          acc[mi][ni] = MFMA16(af[mi], bfr[ni], acc[mi][ni]);
    }
    __syncthreads();
  }

  // epilogue
  for (int ni = 0; ni < 4; ni++){
    int col = tn*128 + wn*64 + ni*16 + (lane & 15);
    float bv = bias ? bias[col] : 0.f;
    for (int mi = 0; mi < 4; mi++){
      f32x4 v = acc[mi][ni];
      int row0 = tm*128 + wm*64 + mi*16 + (lane >> 4)*4;
      if constexpr (EPI == 4){
        if (col < 512){
          for (int j = 0; j < 4; j++){
            size_t idx = (size_t)(row0 + j)*512 + col;
            ((ushort_t*)out)[idx] = f2bf(v[j] + bv);
          }
        } else {
          int hh = (col - 512) >> 6, dd = (col - 512) & 63;
          int bb = row0 >> 6, mm0 = row0 & 63;
          ushort_t pk[4];
          for (int j = 0; j < 4; j++) pk[j] = f2bf(v[j] + bv);
          *(uint2*)((ushort_t*)out2 + ((((size_t)bb*8 + hh)*64 + dd) << 6) + mm0) =
              *(const uint2*)pk;
        }
      } else {
        for (int j = 0; j < 4; j++){
          int row = row0 + j;
          size_t idx = (size_t)row*N + col;
          float x = v[j] + bv;
          if constexpr (EPI == 0) ((ushort_t*)out)[idx] = f2bf(x);
          else if constexpr (EPI == 1) ((float*)out)[idx] = x;
          else if constexpr (EPI == 2) ((float*)out)[idx] = x + resid[idx];
          else if constexpr (EPI == 3){
            float g = 0.5f*x*(1.f + erff(x*0.70710678118f));
            ((ushort_t*)out)[idx] = f2bf(g);
          }
        }
      }
    }
  }
}

// ---------------- batched QK^T ----------------
__global__ __launch_bounds__(256)
void qk_kernel(const ushort_t* __restrict__ Q, const ushort_t* __restrict__ Kb,
               ushort_t* __restrict__ S)
{
  int b = blockIdx.x;
  int wave = threadIdx.x >> 6, lane = threadIdx.x & 63;
  for (int h = wave; h < 8; h += 4){
    f32x4 acc[2][4] = {};
    for (int kk = 0; kk < 2; kk++){
      int kd = kk*32 + (lane >> 4)*8;
      short8 a[2], bb[4];
      for (int mi = 0; mi < 2; mi++){
        int n = mi*16 + (lane & 15); if (n > 16) n = 16;
        a[mi] = *(const short8*)&Q[((size_t)b*17 + n)*512 + h*64 + kd];
      }
      for (int ni = 0; ni < 4; ni++){
        int m = ni*16 + (lane & 15);
        bb[ni] = *(const short8*)&Kb[((size_t)b*64 + m)*512 + h*64 + kd];
      }
      for (int mi = 0; mi < 2; mi++)
        for (int ni = 0; ni < 4; ni++)
          acc[mi][ni] = MFMA16(a[mi], bb[ni], acc[mi][ni]);
    }
    for (int mi = 0; mi < 2; mi++)
      for (int ni = 0; ni < 4; ni++)
        for (int j = 0; j < 4; j++){
          int rr = mi*16 + (lane >> 4)*4 + j;
          if (rr < 17)
            S[((size_t)b*17 + rr)*512 + h*64 + ni*16 + (lane & 15)] =
                f2bf(acc[mi][ni][j]*0.125f);
        }
  }
}

// ---------------- batched PV ----------------
__global__ __launch_bounds__(256)
void pv_kernel(const ushort_t* __restrict__ P, const ushort_t* __restrict__ Vt,
               ushort_t* __restrict__ X)
{
  int b = blockIdx.x;
  int wave = threadIdx.x >> 6, lane = threadIdx.x & 63;
  for (int h = wave; h < 8; h += 4){
    f32x4 acc[2][4] = {};
    for (int kk = 0; kk < 2; kk++){
      int km = kk*32 + (lane >> 4)*8;
      short8 a[2], bb[4];
      for (int mi = 0; mi < 2; mi++){
        int n = mi*16 + (lane & 15); if (n > 16) n = 16;
        a[mi] = *(const short8*)&P[((size_t)b*17 + n)*512 + h*64 + km];
      }
      for (int ni = 0; ni < 4; ni++){
        int d = ni*16 + (lane & 15);
        bb[ni] = *(const short8*)&Vt[(((size_t)b*8 + h)*64 + d)*64 + km];
      }
      for (int mi = 0; mi < 2; mi++)
        for (int ni = 0; ni < 4; ni++)
          acc[mi][ni] = MFMA16(a[mi], bb[ni], acc[mi][ni]);
    }
    for (int mi = 0; mi < 2; mi++)
      for (int ni = 0; ni < 4; ni++)
        for (int j = 0; j < 4; j++){
          int rr = mi*16 + (lane >> 4)*4 + j;
          if (rr < 17)
            X[((size_t)b*17 + rr)*512 + h*64 + ni*16 + (lane & 15)] =
                f2bf(acc[mi][ni][j]);
        }
  }
}

// ---------------- BatchNorm stats ----------------
__global__ __launch_bounds__(256)
void bn_stats(const float* __restrict__ preBN, float* __restrict__ sums){
  int t = threadIdx.x;
  size_t base = (size_t)blockIdx.x * 256 * 512;
  int c0 = t, c1 = t + 256;
  float s0=0, q0=0, s1=0, q1=0;
  for (int r = 0; r < 256; r++){
    float a = preBN[base + (size_t)r*512 + c0];
    float b = preBN[base + (size_t)r*512 + c1];
    s0 += a; q0 += a*a; s1 += b; q1 += b*b;
  }
  atomicAdd(&sums[c0], s0);       atomicAdd(&sums[512 + c0], q0);
  atomicAdd(&sums[c1], s1);       atomicAdd(&sums[512 + c1], q1);
}

__global__ void bn_finalize(const float* __restrict__ sums, const float* __restrict__ g,
                            const float* __restrict__ b, float* __restrict__ scale,
                            float* __restrict__ shift, float invN){
  int c = blockIdx.x*256 + threadIdx.x;
  if (c < 512){
    float mean = sums[c]*invN;
    float var  = sums[512 + c]*invN - mean*mean;
    float sc = g[c]*rsqrtf(var + 1e-5f);
    scale[c] = sc; shift[c] = b[c] - mean*sc;
  }
}

// ---------------- BN apply + adjacency mix + softmax ----------------
__constant__ unsigned ADJM[17] = {
  0x7u, 0xFu, 0x17u, 0x2Au, 0x54u, 0x8E8u, 0x1170u, 0x2A0u, 0x540u,
  0x280u, 0x500u, 0x3820u, 0x5840u, 0xA800u, 0x15000u, 0xA000u, 0x14000u };

__global__ __launch_bounds__(256)
void bn_adj_softmax(const float* __restrict__ preBN, const float* __restrict__ scale,
                    const float* __restrict__ shift, ushort_t* __restrict__ Asm)
{
  __shared__ float yt[17*512];
  int b = blockIdx.x, tid = threadIdx.x;
  const float* src = preBN + (size_t)b*17*512;
  for (int i = tid; i < 17*512; i += 256){
    int c = i & 511;
    yt[i] = src[i]*scale[c] + shift[c];
  }
  __syncthreads();
  int qw = tid >> 4, l16 = tid & 15;
  for (int g = qw; g < 136; g += 16){
    int n = g >> 3, h = g & 7;
    float z[4];
    unsigned msk = ADJM[n];
    for (int u = 0; u < 4; u++){
      int c = h*64 + l16 + u*16;
      float sv = 0.f;
      unsigned mm = msk;
      while (mm){ int j = __ffs(mm) - 1; mm &= mm - 1; sv += yt[j*512 + c]; }
      z[u] = sv;
    }
    float mx = fmaxf(fmaxf(z[0], z[1]), fmaxf(z[2], z[3]));
    for (int m = 8; m; m >>= 1) mx = fmaxf(mx, __shfl_xor(mx, m, 16));
    float e0 = expf(z[0]-mx), e1 = expf(z[1]-mx), e2 = expf(z[2]-mx), e3 = expf(z[3]-mx);
    float ss = e0 + e1 + e2 + e3;
    for (int m = 8; m; m >>= 1) ss += __shfl_xor(ss, m, 16);
    float inv = 1.f/ss;
    size_t ob = ((size_t)b*17 + n)*512 + h*64 + l16;
    Asm[ob]      = f2bf(e0*inv);
    Asm[ob + 16] = f2bf(e1*inv);
    Asm[ob + 32] = f2bf(e2*inv);
    Asm[ob + 48] = f2bf(e3*inv);
  }
}

// ---------------- host ----------------
extern "C" void kernel_launch(void* const* d_in, const int* in_sizes, int n_in,
                              void* d_out, int out_size, void* d_ws, size_t ws_size,
                              hipStream_t stream)
{
  const float* noise  = (const float*)d_in[0];
  const float* obj    = (const float*)d_in[1];
  const float* ln1w   = (const float*)d_in[2];
  const float* ln1b   = (const float*)d_in[3];
  const float* ln2w   = (const float*)d_in[4];
  const float* ln2b   = (const float*)d_in[5];
  const float* q_w    = (const float*)d_in[6];
  const float* kv_w   = (const float*)d_in[7];
  const float* Wm     = (const float*)d_in[8];
  const float* bn_g   = (const float*)d_in[9];
  const float* bn_b   = (const float*)d_in[10];
  const float* proj_w = (const float*)d_in[11];
  const float* proj_b = (const float*)d_in[12];
  const float* fc1_w  = (const float*)d_in[13];
  const float* fc1_b  = (const float*)d_in[14];
  const float* fc2_w  = (const float*)d_in[15];
  const float* fc2_b  = (const float*)d_in[16];

  const int B  = in_sizes[0] / (17*512);   // 2048
  const int M  = B*17;                     // 34816
  const int MO = B*64;                     // 131072

  const size_t MiB = 1ull << 20;
  char* ws = (char*)d_ws;

  // ---- static region: weights & small vectors (0..8 MiB) ----
  ushort_t* q_wb    = (ushort_t*)(ws + 0*MiB);          // 0.5 MiB
  ushort_t* kv_wb   = (ushort_t*)(ws + 1*MiB);          // 1 MiB
  ushort_t* proj_wb = (ushort_t*)(ws + 2*MiB);          // 0.5 MiB
  ushort_t* fc1_wb  = (ushort_t*)(ws + 3*MiB);          // 2 MiB
  ushort_t* fc2_wb  = (ushort_t*)(ws + 5*MiB);          // 2 MiB
  ushort_t* Wt_b    = (ushort_t*)(ws + 7*MiB);          // 0.5 MiB
  float* qbias   = (float*)(ws + 7*MiB + 600*1024);
  float* kvbias  = qbias + 1024;
  float* fc1bias = kvbias + 1024;
  float* bnsum   = fc1bias + 2048;
  float* bnscale = bnsum + 1024;
  float* bnshift = bnscale + 512;

  // ---- big regions (time-shared) ----
  char* R1 = ws + 8*MiB;     // 128 MiB
  char* R2 = ws + 136*MiB;   // 128 MiB
  char* R3 = ws + 264*MiB;   // 128 MiB   (total 392 MiB)

  ushort_t* e1b  = (ushort_t*)R1;               // LN(obj) bf16  [MO,512]
  ushort_t* Kb   = (ushort_t*)R2;               // K bf16        [MO,512]
  ushort_t* Vtb  = (ushort_t*)R3;               // V^T bf16      [B,8,64,64]
  ushort_t* x1b  = (ushort_t*)R1;               // LN(noise) bf16 (after kv)
  ushort_t* Qb   = (ushort_t*)(R1 + 35*MiB);    // Q bf16 [M,512]
  ushort_t* Sb   = (ushort_t*)(R1 + 70*MiB);    // scores bf16 [M,512]
  ushort_t* Asm  = (ushort_t*)R1;               // softmax bf16 (after x1 dead)
  ushort_t* PVo  = (ushort_t*)(R1 + 35*MiB);    // PV out bf16 (after Q dead)
  float*    preBN = (float*)R2;                 // fp32 [M,512] (after K dead)
  float*    xres  = (float*)R2;                 // fp32 [M,512] (after preBN dead)
  ushort_t* yb   = (ushort_t*)(R2 + 69*MiB);    // LN(xres) bf16 [M,512]
  ushort_t* h1   = (ushort_t*)(R2 + 104*MiB);   // gelu(fc1) bf16 [M,2048] (spans into R3)
  float*    outp = (float*)d_out;

  // ---- prep ----
  hipMemsetAsync(bnsum, 0, 1024*4, stream);
  convw<<<dim3((512*512)/256), 256, 0, stream>>>(q_w,  ln1w, q_wb,  512*512, 511);
  convw<<<dim3((1024*512)/256),256, 0, stream>>>(kv_w, ln1w, kv_wb, 1024*512, 511);
  convw<<<dim3((512*512)/256), 256, 0, stream>>>(proj_w, nullptr, proj_wb, 512*512, 511);
  convw<<<dim3((2048*512)/256),256, 0, stream>>>(fc1_w, ln2w, fc1_wb, 2048*512, 511);
  convw<<<dim3((512*2048)/256),256, 0, stream>>>(fc2_w, nullptr, fc2_wb, 512*2048, 2047);
  transw<<<dim3((512*512)/256), 256, 0, stream>>>(Wm, Wt_b);
  biasfold<<<dim3(512),  64, 0, stream>>>(q_w,  ln1b, nullptr, qbias,  512);
  biasfold<<<dim3(1024), 64, 0, stream>>>(kv_w, ln1b, nullptr, kvbias, 512);
  biasfold<<<dim3(2048), 64, 0, stream>>>(fc1_w, ln2b, fc1_b, fc1bias, 512);

  // ---- attention branch ----
  lnorm<<<dim3(MO/4), 256, 0, stream>>>(obj, e1b);
  gemm_k<4><<<dim3((MO/128)*(1024/128)), 256, 0, stream>>>(
      e1b, kv_wb, MO, 1024, 512, kvbias, nullptr, Kb, Vtb);
  lnorm<<<dim3(M/4), 256, 0, stream>>>(noise, x1b);
  gemm_k<0><<<dim3((M/128)*(512/128)), 256, 0, stream>>>(
      x1b, q_wb, M, 512, 512, qbias, nullptr, Qb, nullptr);
  qk_kernel<<<dim3(B), 256, 0, stream>>>(Qb, Kb, Sb);
  gemm_k<1><<<dim3((M/128)*(512/128)), 256, 0, stream>>>(
      Sb, Wt_b, M, 512, 512, nullptr, nullptr, preBN, nullptr);
  bn_stats<<<dim3(M/256), 256, 0, stream>>>(preBN, bnsum);
  bn_finalize<<<dim3(2), 256, 0, stream>>>(bnsum, bn_g, bn_b, bnscale, bnshift, 1.f/(float)M);
  bn_adj_softmax<<<dim3(B), 256, 0, stream>>>(preBN, bnscale, bnshift, Asm);
  pv_kernel<<<dim3(B), 256, 0, stream>>>(Asm, Vtb, PVo);
  gemm_k<2><<<dim3((M/128)*(512/128)), 256, 0, stream>>>(
      PVo, proj_wb, M, 512, 512, proj_b, noise, xres, nullptr);

  // ---- MLP branch ----
  lnorm<<<dim3(M/4), 256, 0, stream>>>(xres, yb);
  gemm_k<3><<<dim3((M/128)*(2048/128)), 256, 0, stream>>>(
      yb, fc1_wb, M, 2048, 512, fc1bias, nullptr, h1, nullptr);
  gemm_k<2><<<dim3((M/128)*(512/128)), 256, 0, stream>>>(
      h1, fc2_wb, M, 512, 2048, fc2_b, xres, outp, nullptr);
}

// Round 3
// 990.200 us; speedup vs baseline: 1.2379x; 1.0206x over previous
//
#include <hip/hip_runtime.h>
#include <math.h>

typedef unsigned short ushort_t;
typedef short short8 __attribute__((ext_vector_type(8)));
typedef float f32x4 __attribute__((ext_vector_type(4)));

#define MFMA16(a,b,c) __builtin_amdgcn_mfma_f32_16x16x32_bf16(a,b,c,0,0,0)

__device__ __forceinline__ ushort_t f2bf(float f){
  unsigned u = __builtin_bit_cast(unsigned, f);
  u += 0x7fffu + ((u >> 16) & 1u);
  return (ushort_t)(u >> 16);
}

__device__ __forceinline__ void gld16(const void* g, void* l){
  __builtin_amdgcn_global_load_lds(
      (const __attribute__((address_space(1))) void*)g,
      (__attribute__((address_space(3))) void*)l, 16, 0, 0);
}

// ---------------- merged weight prep ----------------
// segments (element-linear):
// 0: q_wb    = bf16(q_w * ln1w[k])        262144
// 1: kv_wb   = bf16(kv_w * ln1w[k])       524288
// 2: proj_wb = bf16(proj_w)               262144
// 3: fc1_wb  = bf16(fc1_w * ln2w[k])     1048576
// 4: fc2_wb  = bf16(fc2_w)               1048576
// 5: Wt_b[n,k] = bf16(W[k,n])             262144
__global__ __launch_bounds__(256)
void prep_weights(const float* __restrict__ q_w, const float* __restrict__ kv_w,
                  const float* __restrict__ proj_w, const float* __restrict__ fc1_w,
                  const float* __restrict__ fc2_w, const float* __restrict__ Wm,
                  const float* __restrict__ ln1w, const float* __restrict__ ln2w,
                  ushort_t* __restrict__ q_wb, ushort_t* __restrict__ kv_wb,
                  ushort_t* __restrict__ proj_wb, ushort_t* __restrict__ fc1_wb,
                  ushort_t* __restrict__ fc2_wb, ushort_t* __restrict__ Wt_b)
{
  int i = blockIdx.x*256 + threadIdx.x;
  if (i < 262144){
    q_wb[i] = f2bf(q_w[i] * ln1w[i & 511]);
  } else if (i < 786432){
    int j = i - 262144;
    kv_wb[j] = f2bf(kv_w[j] * ln1w[j & 511]);
  } else if (i < 1048576){
    int j = i - 786432;
    proj_wb[j] = f2bf(proj_w[j]);
  } else if (i < 2097152){
    int j = i - 1048576;
    fc1_wb[j] = f2bf(fc1_w[j] * ln2w[j & 511]);
  } else if (i < 3145728){
    int j = i - 2097152;
    fc2_wb[j] = f2bf(fc2_w[j]);
  } else if (i < 3407872){
    int j = i - 3145728;
    int n = j >> 9, k = j & 511;
    Wt_b[j] = f2bf(Wm[(k << 9) + n]);
  }
}

// merged bias folding: blocks 0..511 q, 512..1535 kv, 1536..3583 fc1
__global__ __launch_bounds__(64)
void prep_bias(const float* __restrict__ q_w, const float* __restrict__ kv_w,
               const float* __restrict__ fc1_w, const float* __restrict__ ln1b,
               const float* __restrict__ ln2b, const float* __restrict__ fc1_b,
               float* __restrict__ qbias, float* __restrict__ kvbias,
               float* __restrict__ fc1bias)
{
  int blk = blockIdx.x, lane = threadIdx.x;
  const float* w; const float* lnb; float* o; float base = 0.f; int n;
  if (blk < 512){ n = blk; w = q_w; lnb = ln1b; o = qbias; }
  else if (blk < 1536){ n = blk - 512; w = kv_w; lnb = ln1b; o = kvbias; }
  else { n = blk - 1536; w = fc1_w; lnb = ln2b; o = fc1bias; }
  float s = 0.f;
  for (int k = lane; k < 512; k += 64) s += w[(size_t)n*512 + k]*lnb[k];
  for (int m = 32; m; m >>= 1) s += __shfl_xor(s, m);
  if (lane == 0){
    if (blk >= 1536) base = fc1_b[n];
    o[n] = s + base;
  }
}

// ---------------- fused LN stats + normalize -> bf16 ----------------
__global__ __launch_bounds__(256)
void lnorm(const float* __restrict__ X, ushort_t* __restrict__ O){
  int row = blockIdx.x*4 + (threadIdx.x >> 6);
  int lane = threadIdx.x & 63;
  const float4* p = (const float4*)(X + (size_t)row*512 + lane*8);
  float4 a = p[0], c = p[1];
  float s = a.x+a.y+a.z+a.w + c.x+c.y+c.z+c.w;
  float q = a.x*a.x+a.y*a.y+a.z*a.z+a.w*a.w + c.x*c.x+c.y*c.y+c.z*c.z+c.w*c.w;
  for (int m = 32; m; m >>= 1){ s += __shfl_xor(s, m); q += __shfl_xor(q, m); }
  float mn = s*(1.f/512.f);
  float rs = rsqrtf(q*(1.f/512.f) - mn*mn + 1e-5f);
  short8 pk;
  pk[0]=(short)f2bf((a.x-mn)*rs); pk[1]=(short)f2bf((a.y-mn)*rs);
  pk[2]=(short)f2bf((a.z-mn)*rs); pk[3]=(short)f2bf((a.w-mn)*rs);
  pk[4]=(short)f2bf((c.x-mn)*rs); pk[5]=(short)f2bf((c.y-mn)*rs);
  pk[6]=(short)f2bf((c.z-mn)*rs); pk[7]=(short)f2bf((c.w-mn)*rs);
  *(short8*)(O + (size_t)row*512 + lane*8) = pk;
}

// ---------------- GEMM: C[M,N] = A[M,K] * Bt[N,K]^T (A,Bt bf16) ----------------
// XCD-aware chunked block swizzle (bijective): HW block i runs on XCD i%8;
// logical tile = chunkbase(i%8) + i/8, so logically-consecutive tiles (which
// share an A panel) execute back-to-back on ONE XCD -> L2 hit.
// LDS tiles XOR-swizzled via pre-swizzled global source (gld16 dest linear).
// EPI 0: bf16 out (+bias)             1: fp32 out
// EPI 2: fp32 out = acc+bias+resid    3: bf16 out = gelu(acc+bias)
// EPI 4: KV split: cols<512 -> bf16 K[M,512]; cols>=512 -> Vt[b,h,d,m] (out2)
template<int EPI>
__global__ __launch_bounds__(256)
void gemm_k(const ushort_t* __restrict__ A, const ushort_t* __restrict__ Bt,
            int M, int N, int K,
            const float* __restrict__ bias, const float* __restrict__ resid,
            void* __restrict__ out, void* __restrict__ out2)
{
  __shared__ __align__(16) ushort_t As[128*64];
  __shared__ __align__(16) ushort_t Bs[128*64];
  const int tid = threadIdx.x;
  const int wave = tid >> 6, lane = tid & 63;

  // bijective XCD swizzle
  const int nwg = gridDim.x;
  const int qc = nwg >> 3, rc = nwg & 7;
  const int xcd = blockIdx.x & 7, sl = blockIdx.x >> 3;
  const int bid = (xcd < rc ? xcd*(qc+1) : rc*(qc+1) + (xcd-rc)*qc) + sl;

  const int tiles_n = N >> 7;
  const int tn = bid % tiles_n, tm = bid / tiles_n;
  const int wm = wave >> 1, wn = wave & 1;
  const int segr = lane >> 3;                    // row within 8-row segment
  const int ksw  = ((lane & 7) ^ segr) * 8;      // pre-swizzled k source col

  f32x4 acc[4][4] = {};

  for (int kt = 0; kt < K; kt += 64){
    for (int i = 0; i < 4; i++){
      int seg = wave*4 + i;
      int row = seg*8 + segr;
      gld16(Bt + (size_t)(tn*128 + row)*K + kt + ksw, (void*)(Bs + seg*512));
      gld16(A  + (size_t)(tm*128 + row)*K + kt + ksw, (void*)(As + seg*512));
    }
    __syncthreads();
    for (int kk = 0; kk < 2; kk++){
      int kc = kk*32 + (lane >> 4)*8;
      short8 af[4], bfr[4];
      for (int mi = 0; mi < 4; mi++){
        int r = wm*64 + mi*16 + (lane & 15);
        af[mi] = *(const short8*)&As[r*64 + (kc ^ ((r & 7) << 3))];
      }
      for (int ni = 0; ni < 4; ni++){
        int r = wn*64 + ni*16 + (lane & 15);
        bfr[ni] = *(const short8*)&Bs[r*64 + (kc ^ ((r & 7) << 3))];
      }
      for (int mi = 0; mi < 4; mi++)
        for (int ni = 0; ni < 4; ni++)
          acc[mi][ni] = MFMA16(af[mi], bfr[ni], acc[mi][ni]);
    }
    __syncthreads();
  }

  // epilogue
  for (int ni = 0; ni < 4; ni++){
    int col = tn*128 + wn*64 + ni*16 + (lane & 15);
    float bv = bias ? bias[col] : 0.f;
    for (int mi = 0; mi < 4; mi++){
      f32x4 v = acc[mi][ni];
      int row0 = tm*128 + wm*64 + mi*16 + (lane >> 4)*4;
      if constexpr (EPI == 4){
        if (col < 512){
          for (int j = 0; j < 4; j++){
            size_t idx = (size_t)(row0 + j)*512 + col;
            ((ushort_t*)out)[idx] = f2bf(v[j] + bv);
          }
        } else {
          int hh = (col - 512) >> 6, dd = (col - 512) & 63;
          int bb = row0 >> 6, mm0 = row0 & 63;
          ushort_t pk[4];
          for (int j = 0; j < 4; j++) pk[j] = f2bf(v[j] + bv);
          *(uint2*)((ushort_t*)out2 + ((((size_t)bb*8 + hh)*64 + dd) << 6) + mm0) =
              *(const uint2*)pk;
        }
      } else {
        for (int j = 0; j < 4; j++){
          int row = row0 + j;
          size_t idx = (size_t)row*N + col;
          float x = v[j] + bv;
          if constexpr (EPI == 0) ((ushort_t*)out)[idx] = f2bf(x);
          else if constexpr (EPI == 1) ((float*)out)[idx] = x;
          else if constexpr (EPI == 2) ((float*)out)[idx] = x + resid[idx];
          else if constexpr (EPI == 3){
            float g = 0.5f*x*(1.f + erff(x*0.70710678118f));
            ((ushort_t*)out)[idx] = f2bf(g);
          }
        }
      }
    }
  }
}

// ---------------- batched QK^T ----------------
__global__ __launch_bounds__(256)
void qk_kernel(const ushort_t* __restrict__ Q, const ushort_t* __restrict__ Kb,
               ushort_t* __restrict__ S)
{
  int b = blockIdx.x;
  int wave = threadIdx.x >> 6, lane = threadIdx.x & 63;
  for (int h = wave; h < 8; h += 4){
    f32x4 acc[2][4] = {};
    for (int kk = 0; kk < 2; kk++){
      int kd = kk*32 + (lane >> 4)*8;
      short8 a[2], bb[4];
      for (int mi = 0; mi < 2; mi++){
        int n = mi*16 + (lane & 15); if (n > 16) n = 16;
        a[mi] = *(const short8*)&Q[((size_t)b*17 + n)*512 + h*64 + kd];
      }
      for (int ni = 0; ni < 4; ni++){
        int m = ni*16 + (lane & 15);
        bb[ni] = *(const short8*)&Kb[((size_t)b*64 + m)*512 + h*64 + kd];
      }
      for (int mi = 0; mi < 2; mi++)
        for (int ni = 0; ni < 4; ni++)
          acc[mi][ni] = MFMA16(a[mi], bb[ni], acc[mi][ni]);
    }
    for (int mi = 0; mi < 2; mi++)
      for (int ni = 0; ni < 4; ni++)
        for (int j = 0; j < 4; j++){
          int rr = mi*16 + (lane >> 4)*4 + j;
          if (rr < 17)
            S[((size_t)b*17 + rr)*512 + h*64 + ni*16 + (lane & 15)] =
                f2bf(acc[mi][ni][j]*0.125f);
        }
  }
}

// ---------------- batched PV ----------------
__global__ __launch_bounds__(256)
void pv_kernel(const ushort_t* __restrict__ P, const ushort_t* __restrict__ Vt,
               ushort_t* __restrict__ X)
{
  int b = blockIdx.x;
  int wave = threadIdx.x >> 6, lane = threadIdx.x & 63;
  for (int h = wave; h < 8; h += 4){
    f32x4 acc[2][4] = {};
    for (int kk = 0; kk < 2; kk++){
      int km = kk*32 + (lane >> 4)*8;
      short8 a[2], bb[4];
      for (int mi = 0; mi < 2; mi++){
        int n = mi*16 + (lane & 15); if (n > 16) n = 16;
        a[mi] = *(const short8*)&P[((size_t)b*17 + n)*512 + h*64 + km];
      }
      for (int ni = 0; ni < 4; ni++){
        int d = ni*16 + (lane & 15);
        bb[ni] = *(const short8*)&Vt[(((size_t)b*8 + h)*64 + d)*64 + km];
      }
      for (int mi = 0; mi < 2; mi++)
        for (int ni = 0; ni < 4; ni++)
          acc[mi][ni] = MFMA16(a[mi], bb[ni], acc[mi][ni]);
    }
    for (int mi = 0; mi < 2; mi++)
      for (int ni = 0; ni < 4; ni++)
        for (int j = 0; j < 4; j++){
          int rr = mi*16 + (lane >> 4)*4 + j;
          if (rr < 17)
            X[((size_t)b*17 + rr)*512 + h*64 + ni*16 + (lane & 15)] =
                f2bf(acc[mi][ni][j]);
        }
  }
}

// ---------------- BatchNorm stats ----------------
__global__ __launch_bounds__(256)
void bn_stats(const float* __restrict__ preBN, float* __restrict__ sums){
  int t = threadIdx.x;
  size_t base = (size_t)blockIdx.x * 256 * 512;
  int c0 = t, c1 = t + 256;
  float s0=0, q0=0, s1=0, q1=0;
  for (int r = 0; r < 256; r++){
    float a = preBN[base + (size_t)r*512 + c0];
    float b = preBN[base + (size_t)r*512 + c1];
    s0 += a; q0 += a*a; s1 += b; q1 += b*b;
  }
  atomicAdd(&sums[c0], s0);       atomicAdd(&sums[512 + c0], q0);
  atomicAdd(&sums[c1], s1);       atomicAdd(&sums[512 + c1], q1);
}

__global__ void bn_finalize(const float* __restrict__ sums, const float* __restrict__ g,
                            const float* __restrict__ b, float* __restrict__ scale,
                            float* __restrict__ shift, float invN){
  int c = blockIdx.x*256 + threadIdx.x;
  if (c < 512){
    float mean = sums[c]*invN;
    float var  = sums[512 + c]*invN - mean*mean;
    float sc = g[c]*rsqrtf(var + 1e-5f);
    scale[c] = sc; shift[c] = b[c] - mean*sc;
  }
}

// ---------------- BN apply + adjacency mix + softmax ----------------
__constant__ unsigned ADJM[17] = {
  0x7u, 0xFu, 0x17u, 0x2Au, 0x54u, 0x8E8u, 0x1170u, 0x2A0u, 0x540u,
  0x280u, 0x500u, 0x3820u, 0x5840u, 0xA800u, 0x15000u, 0xA000u, 0x14000u };

__global__ __launch_bounds__(256)
void bn_adj_softmax(const float* __restrict__ preBN, const float* __restrict__ scale,
                    const float* __restrict__ shift, ushort_t* __restrict__ Asm)
{
  __shared__ float yt[17*512];
  int b = blockIdx.x, tid = threadIdx.x;
  const float* src = preBN + (size_t)b*17*512;
  for (int i = tid; i < 17*512; i += 256){
    int c = i & 511;
    yt[i] = src[i]*scale[c] + shift[c];
  }
  __syncthreads();
  int qw = tid >> 4, l16 = tid & 15;
  for (int g = qw; g < 136; g += 16){
    int n = g >> 3, h = g & 7;
    float z[4];
    unsigned msk = ADJM[n];
    for (int u = 0; u < 4; u++){
      int c = h*64 + l16 + u*16;
      float sv = 0.f;
      unsigned mm = msk;
      while (mm){ int j = __ffs(mm) - 1; mm &= mm - 1; sv += yt[j*512 + c]; }
      z[u] = sv;
    }
    float mx = fmaxf(fmaxf(z[0], z[1]), fmaxf(z[2], z[3]));
    for (int m = 8; m; m >>= 1) mx = fmaxf(mx, __shfl_xor(mx, m, 16));
    float e0 = expf(z[0]-mx), e1 = expf(z[1]-mx), e2 = expf(z[2]-mx), e3 = expf(z[3]-mx);
    float ss = e0 + e1 + e2 + e3;
    for (int m = 8; m; m >>= 1) ss += __shfl_xor(ss, m, 16);
    float inv = 1.f/ss;
    size_t ob = ((size_t)b*17 + n)*512 + h*64 + l16;
    Asm[ob]      = f2bf(e0*inv);
    Asm[ob + 16] = f2bf(e1*inv);
    Asm[ob + 32] = f2bf(e2*inv);
    Asm[ob + 48] = f2bf(e3*inv);
  }
}

// ---------------- host ----------------
extern "C" void kernel_launch(void* const* d_in, const int* in_sizes, int n_in,
                              void* d_out, int out_size, void* d_ws, size_t ws_size,
                              hipStream_t stream)
{
  const float* noise  = (const float*)d_in[0];
  const float* obj    = (const float*)d_in[1];
  const float* ln1w   = (const float*)d_in[2];
  const float* ln1b   = (const float*)d_in[3];
  const float* ln2w   = (const float*)d_in[4];
  const float* ln2b   = (const float*)d_in[5];
  const float* q_w    = (const float*)d_in[6];
  const float* kv_w   = (const float*)d_in[7];
  const float* Wm     = (const float*)d_in[8];
  const float* bn_g   = (const float*)d_in[9];
  const float* bn_b   = (const float*)d_in[10];
  const float* proj_w = (const float*)d_in[11];
  const float* proj_b = (const float*)d_in[12];
  const float* fc1_w  = (const float*)d_in[13];
  const float* fc1_b  = (const float*)d_in[14];
  const float* fc2_w  = (const float*)d_in[15];
  const float* fc2_b  = (const float*)d_in[16];

  const int B  = in_sizes[0] / (17*512);   // 2048
  const int M  = B*17;                     // 34816
  const int MO = B*64;                     // 131072

  const size_t MiB = 1ull << 20;
  char* ws = (char*)d_ws;

  // ---- static region: weights & small vectors (0..8 MiB) ----
  ushort_t* q_wb    = (ushort_t*)(ws + 0*MiB);          // 0.5 MiB
  ushort_t* kv_wb   = (ushort_t*)(ws + 1*MiB);          // 1 MiB
  ushort_t* proj_wb = (ushort_t*)(ws + 2*MiB);          // 0.5 MiB
  ushort_t* fc1_wb  = (ushort_t*)(ws + 3*MiB);          // 2 MiB
  ushort_t* fc2_wb  = (ushort_t*)(ws + 5*MiB);          // 2 MiB
  ushort_t* Wt_b    = (ushort_t*)(ws + 7*MiB);          // 0.5 MiB
  float* qbias   = (float*)(ws + 7*MiB + 600*1024);
  float* kvbias  = qbias + 1024;
  float* fc1bias = kvbias + 1024;
  float* bnsum   = fc1bias + 2048;
  float* bnscale = bnsum + 1024;
  float* bnshift = bnscale + 512;

  // ---- big regions (time-shared) ----
  char* R1 = ws + 8*MiB;     // 128 MiB
  char* R2 = ws + 136*MiB;   // 128 MiB
  char* R3 = ws + 264*MiB;   // 128 MiB   (total 392 MiB)

  ushort_t* e1b  = (ushort_t*)R1;               // LN(obj) bf16  [MO,512]
  ushort_t* Kb   = (ushort_t*)R2;               // K bf16        [MO,512]
  ushort_t* Vtb  = (ushort_t*)R3;               // V^T bf16      [B,8,64,64]
  ushort_t* x1b  = (ushort_t*)R1;               // LN(noise) bf16 (after kv)
  ushort_t* Qb   = (ushort_t*)(R1 + 35*MiB);    // Q bf16 [M,512]
  ushort_t* Sb   = (ushort_t*)(R1 + 70*MiB);    // scores bf16 [M,512]
  ushort_t* Asm  = (ushort_t*)R1;               // softmax bf16 (after x1 dead)
  ushort_t* PVo  = (ushort_t*)(R1 + 35*MiB);    // PV out bf16 (after Q dead)
  float*    preBN = (float*)R2;                 // fp32 [M,512] (after K dead)
  float*    xres  = (float*)R2;                 // fp32 [M,512] (after preBN dead)
  ushort_t* yb   = (ushort_t*)(R2 + 69*MiB);    // LN(xres) bf16 [M,512]
  ushort_t* h1   = (ushort_t*)(R2 + 104*MiB);   // gelu(fc1) bf16 [M,2048] (spans into R3)
  float*    outp = (float*)d_out;

  // ---- prep ----
  hipMemsetAsync(bnsum, 0, 1024*4, stream);
  prep_weights<<<dim3(3407872/256), 256, 0, stream>>>(
      q_w, kv_w, proj_w, fc1_w, fc2_w, Wm, ln1w, ln2w,
      q_wb, kv_wb, proj_wb, fc1_wb, fc2_wb, Wt_b);
  prep_bias<<<dim3(3584), 64, 0, stream>>>(
      q_w, kv_w, fc1_w, ln1b, ln2b, fc1_b, qbias, kvbias, fc1bias);

  // ---- attention branch ----
  lnorm<<<dim3(MO/4), 256, 0, stream>>>(obj, e1b);
  gemm_k<4><<<dim3((MO/128)*(1024/128)), 256, 0, stream>>>(
      e1b, kv_wb, MO, 1024, 512, kvbias, nullptr, Kb, Vtb);
  lnorm<<<dim3(M/4), 256, 0, stream>>>(noise, x1b);
  gemm_k<0><<<dim3((M/128)*(512/128)), 256, 0, stream>>>(
      x1b, q_wb, M, 512, 512, qbias, nullptr, Qb, nullptr);
  qk_kernel<<<dim3(B), 256, 0, stream>>>(Qb, Kb, Sb);
  gemm_k<1><<<dim3((M/128)*(512/128)), 256, 0, stream>>>(
      Sb, Wt_b, M, 512, 512, nullptr, nullptr, preBN, nullptr);
  bn_stats<<<dim3(M/256), 256, 0, stream>>>(preBN, bnsum);
  bn_finalize<<<dim3(2), 256, 0, stream>>>(bnsum, bn_g, bn_b, bnscale, bnshift, 1.f/(float)M);
  bn_adj_softmax<<<dim3(B), 256, 0, stream>>>(preBN, bnscale, bnshift, Asm);
  pv_kernel<<<dim3(B), 256, 0, stream>>>(Asm, Vtb, PVo);
  gemm_k<2><<<dim3((M/128)*(512/128)), 256, 0, stream>>>(
      PVo, proj_wb, M, 512, 512, proj_b, noise, xres, nullptr);

  // ---- MLP branch ----
  lnorm<<<dim3(M/4), 256, 0, stream>>>(xres, yb);
  gemm_k<3><<<dim3((M/128)*(2048/128)), 256, 0, stream>>>(
      yb, fc1_wb, M, 2048, 512, fc1bias, nullptr, h1, nullptr);
  gemm_k<2><<<dim3((M/128)*(512/128)), 256, 0, stream>>>(
      h1, fc2_wb, M, 512, 2048, fc2_b, xres, outp, nullptr);
}